// Round 4
// baseline (134.795 us; speedup 1.0000x reference)
//
#include <hip/hip_runtime.h>
#include <hip/hip_bf16.h>

// Problem: B=32, S=512, P=512, D=768
//   M = B*S = 16384 tokens, N = P = 512 prototypes, K = D = 768
// out[0 .. M*N)            = distances  ||x_m - p_n||^2  (fp32)
// out[M*N .. M*N + N*K)    = prototypes (fp32 passthrough)
//
// R9 = R8 per-wave code, 4 blocks/CU.
//   R5/R7/R8: three different schedules, all 44-48 us, all pipes idle
//   (Mfma ~9%, VALU ~8%, HBM ~17%, Occ ~26%) -> concurrency starvation:
//   ~8 waves/CU can't cover L2/L3 latency (bytes-in-flight ~1.5KB/CU vs
//   ~6KB needed). Fix: 4-wave blocks (64 tok x 128 protos), grid 1024,
//   LDS 35KB -> 4 blocks/CU (140KB), 16 waves/CU even at <=128 VGPR.
//   Per-wave inner loop identical to verified R8 (32 protos x 64 tokens,
//   acc[2][4], depth-2 proto prefetch, K-chunk-128 dbuf staging).
//   XCD swizzle: the 4 N-quarters of a stripe land consecutively on one
//   XCD -> stripe's X read is L2-hot for 3 of 4 blocks.

#define M_TOK 16384
#define N_PROT 512
#define K_DIM 768
#define BKC 128              // K-chunk staged in LDS
#define NKC (K_DIM / BKC)    // 6
#define NSK (K_DIM / 32)     // 24 MFMA k-steps
#define ASTR 136             // LDS row stride (bf16 units): 128 + 8 pad

typedef __attribute__((ext_vector_type(4))) float f32x4;
typedef __attribute__((ext_vector_type(8))) short bf16x8;

__device__ inline unsigned short f2bf(float f) {
    unsigned int u = __float_as_uint(f);
    u += 0x7fffu + ((u >> 16) & 1u);
    return (unsigned short)(u >> 16);
}

// One wave per prototype row: bf16 convert + ||p||^2 + fp32 passthrough copy.
__global__ __launch_bounds__(256) void prep_b(
    const float* __restrict__ p,
    unsigned short* __restrict__ b_bf, float* __restrict__ p_sq,
    float* __restrict__ proto_out)
{
    const int row  = blockIdx.x * 4 + (threadIdx.x >> 6);
    const int lane = threadIdx.x & 63;

    const float4* src4 = (const float4*)(p + (size_t)row * K_DIM);
    unsigned short* dst = b_bf + (size_t)row * K_DIM;
    float4* pout4 = (float4*)(proto_out + (size_t)row * K_DIM);

    float ssum = 0.0f;
#pragma unroll
    for (int j = 0; j < 3; ++j) {
        const int idx = lane + j * 64;
        float4 v = src4[idx];
        ssum += v.x * v.x + v.y * v.y + v.z * v.z + v.w * v.w;
        ushort4 b;
        b.x = f2bf(v.x); b.y = f2bf(v.y); b.z = f2bf(v.z); b.w = f2bf(v.w);
        ((ushort4*)dst)[idx] = b;
        pout4[idx] = v;
    }
#pragma unroll
    for (int off = 32; off > 0; off >>= 1) ssum += __shfl_down(ssum, off);
    if (lane == 0) p_sq[row] = ssum;
}

__global__ __launch_bounds__(256, 4) void dist_main(
    const float* __restrict__ X,             // [M,K] fp32 tokens
    const unsigned short* __restrict__ Bb,   // [N,K] bf16 prototypes (ws)
    const float* __restrict__ p_sq,          // [N] fp32
    float* __restrict__ out)                 // [M,N] fp32 distances
{
    __shared__ unsigned short lds_a[2][64 * ASTR];   // 2 x 17408 B = 34816 B
    __shared__ float lds_xsq[64];

    // ---- block mapping: XCD-chunked swizzle, quartet-adjacent N-quarters ----
    // hw block b -> XCD b%8 (dispatch heuristic). logical id walks 128-runs
    // per XCD; the 4 N-quarters of one stripe are consecutive -> same XCD.
    const int bid     = blockIdx.x;                     // 0..1023
    const int logical = (bid & 7) * 128 + (bid >> 3);   // bijective 0..1023
    const int ms = logical >> 2;                        // M-stripe 0..255
    const int nq = logical & 3;                         // N quarter
    const int bm = ms << 6;
    const int bn = nq << 7;

    const int tid  = threadIdx.x;
    const int wave = tid >> 6;           // 0..3
    const int lane = tid & 63;
    const int wn   = bn + (wave << 5);   // wave's 32-proto slice of N
    const int quad = lane >> 4;          // 0..3
    const int l16  = lane & 15;

    // ---- staging mapping: 256 thr stage a 64x128 fp32 chunk (8 float4/thr) ----
    const int ar = tid >> 2;             // row 0..63
    const int ac = tid & 3;              // float4 col base (0..3)
    const float* aptr = X + (size_t)(bm + ar) * K_DIM + ac * 4;

    float asq = 0.0f;

    // prologue: stage chunk 0 (float4 idx = ac + 4*j, j=0..7)
    {
#pragma unroll
        for (int j = 0; j < 8; ++j) {
            float4 v = *(const float4*)(aptr + 16 * j);
            asq += v.x * v.x + v.y * v.y + v.z * v.z + v.w * v.w;
            ushort4 u;
            u.x = f2bf(v.x); u.y = f2bf(v.y); u.z = f2bf(v.z); u.w = f2bf(v.w);
            *(ushort4*)&lds_a[0][ar * ASTR + (ac + 4 * j) * 4] = u;
        }
    }
    __syncthreads();

    // ---- proto (A-operand) fragments: global->VGPR, depth-2 pipeline ----
    // lane holds proto row (wn + pt*16 + l16), k-slice quad*8 + [0,8)
    const unsigned short* pb = Bb + (size_t)(wn + l16) * K_DIM + quad * 8;

    bf16x8 A0[2], A1[2], A2[2];
    A0[0] = *(const bf16x8*)(pb);
    A0[1] = *(const bf16x8*)(pb + 16 * K_DIM);
    A1[0] = *(const bf16x8*)(pb + 32);
    A1[1] = *(const bf16x8*)(pb + 16 * K_DIM + 32);

    const f32x4 zero = {0.0f, 0.0f, 0.0f, 0.0f};
    f32x4 acc[2][4];                     // [proto group][token group]
#pragma unroll
    for (int pt = 0; pt < 2; ++pt)
#pragma unroll
        for (int tt = 0; tt < 4; ++tt) acc[pt][tt] = zero;

    for (int kc = 0; kc < NKC; ++kc) {
        // issue next A-chunk global loads early (hide under this chunk's MFMAs)
        float4 s[8];
        if (kc + 1 < NKC) {
            const float* ap = aptr + (kc + 1) * BKC;
#pragma unroll
            for (int j = 0; j < 8; ++j) s[j] = *(const float4*)(ap + 16 * j);
        }

#pragma unroll
        for (int ss = 0; ss < 4; ++ss) {
            const int kk = kc * 4 + ss;
            if (kk + 2 < NSK) {          // uniform scalar branch, depth-2
                const int kn = (kk + 2) * 32;
                A2[0] = *(const bf16x8*)(pb + kn);
                A2[1] = *(const bf16x8*)(pb + 16 * K_DIM + kn);
            }

            bf16x8 tf[4];                // token (B-operand) frags from LDS
#pragma unroll
            for (int tt = 0; tt < 4; ++tt)
                tf[tt] = *(const bf16x8*)&lds_a[kc & 1]
                    [(tt * 16 + l16) * ASTR + ss * 32 + quad * 8];

#pragma unroll
            for (int tt = 0; tt < 4; ++tt) {
                acc[0][tt] = __builtin_amdgcn_mfma_f32_16x16x32_bf16(
                    A0[0], tf[tt], acc[0][tt], 0, 0, 0);
                acc[1][tt] = __builtin_amdgcn_mfma_f32_16x16x32_bf16(
                    A0[1], tf[tt], acc[1][tt], 0, 0, 0);
            }
            A0[0] = A1[0]; A0[1] = A1[1];
            A1[0] = A2[0]; A1[1] = A2[1];
        }

        // convert + write next chunk into the other buffer, then one barrier
        if (kc + 1 < NKC) {
            unsigned short* aw = &lds_a[(kc + 1) & 1][ar * ASTR + ac * 4];
#pragma unroll
            for (int j = 0; j < 8; ++j) {
                float4 v = s[j];
                asq += v.x * v.x + v.y * v.y + v.z * v.z + v.w * v.w;
                ushort4 u;
                u.x = f2bf(v.x); u.y = f2bf(v.y); u.z = f2bf(v.z); u.w = f2bf(v.w);
                *(ushort4*)(aw + 4 * j * 4) = u;
            }
        }
        __syncthreads();
    }

    // ---- x_sq: reduce over the 4 staging threads of each row ----
#pragma unroll
    for (int off = 1; off < 4; off <<= 1) asq += __shfl_xor(asq, off);
    if (ac == 0) lds_xsq[ar] = asq;
    __syncthreads();

    // ---- epilogue (swapped layout): D row = proto = quad*4+i, col = token = l16
    //      -> 4 acc regs are 4 consecutive protos -> float4 stores ----
    float4 ps4[2];
    ps4[0] = *(const float4*)&p_sq[wn + quad * 4];
    ps4[1] = *(const float4*)&p_sq[wn + 16 + quad * 4];

#pragma unroll
    for (int tt = 0; tt < 4; ++tt) {
        const float xs = lds_xsq[tt * 16 + l16];
        float* orow = out + (size_t)(bm + tt * 16 + l16) * N_PROT + wn + quad * 4;
        float4 o0, o1;
        o0.x = xs + ps4[0].x - 2.0f * acc[0][tt][0];
        o0.y = xs + ps4[0].y - 2.0f * acc[0][tt][1];
        o0.z = xs + ps4[0].z - 2.0f * acc[0][tt][2];
        o0.w = xs + ps4[0].w - 2.0f * acc[0][tt][3];
        o1.x = xs + ps4[1].x - 2.0f * acc[1][tt][0];
        o1.y = xs + ps4[1].y - 2.0f * acc[1][tt][1];
        o1.z = xs + ps4[1].z - 2.0f * acc[1][tt][2];
        o1.w = xs + ps4[1].w - 2.0f * acc[1][tt][3];
        *(float4*)(orow)      = o0;
        *(float4*)(orow + 16) = o1;
    }
}

extern "C" void kernel_launch(void* const* d_in, const int* in_sizes, int n_in,
                              void* d_out, int out_size, void* d_ws, size_t ws_size,
                              hipStream_t stream) {
    const float* inputs = (const float*)d_in[0];   // [32,512,768] fp32
    const float* protos = (const float*)d_in[1];   // [512,768]    fp32
    float* out = (float*)d_out;
    float* proto_out = out + (size_t)M_TOK * N_PROT;   // second tuple element

    // ws layout: b_bf 512*768*2 = 786,432 B ; p_sq 512*4 = 2,048 B
    char* ws = (char*)d_ws;
    unsigned short* b_bf = (unsigned short*)ws;
    float* p_sq = (float*)(ws + 786432);

    prep_b<<<128, 256, 0, stream>>>(protos, b_bf, p_sq, proto_out);
    // 256 M-stripes x 4 N-quarters = 1024 blocks, 4 blocks/CU
    dist_main<<<1024, 256, 0, stream>>>(inputs, b_bf, p_sq, out);
}

// Round 5
// 102.637 us; speedup vs baseline: 1.3133x; 1.3133x over previous
//
#include <hip/hip_runtime.h>
#include <hip/hip_bf16.h>

// Problem: B=32, S=512, P=512, D=768
//   M = B*S = 16384 tokens, N = P = 512 prototypes, K = D = 768
// out[0 .. M*N)            = distances  ||x_m - p_n||^2  (fp32)
// out[M*N .. M*N + N*K)    = prototypes (fp32 passthrough)
//
// R10 = R5 (best measured, 44.3us) + fragment-major B layout in ws.
//   R5/R7/R8/R9: four schedules, 44-59us, all pipes idle. R9 refuted the
//   occupancy theory (more waves = slower). Shared invariant of all four:
//   B-fragment loads gather 16 proto rows at stride 1536B -> 16 scattered
//   64B segments PER INSTRUCTION (~12K serialized L2 requests/CU) and a
//   divergent-address latency the depth-1 prefetch can't hide.
//   Fix: prep_b stores b_bf FRAGMENT-MAJOR: for (proto-group g, k-step kk)
//   the 64 lanes' 16B fragments are one contiguous 1KB block at
//   ((g*24+kk)*1024). dist_main's B-load becomes base + lane*16 = the ideal
//   coalesced wave load (1KB/instr, sequential stream per group across kk).
//   Per-lane fragment data is BIT-IDENTICAL to verified R5 (lane&15 = proto
//   row, lane>>4 = k-slice quad, 8 consecutive k); only addresses changed.
//   Everything else byte-identical to R5 (full-K stripe, ONE barrier,
//   depth-1 rotation, dword epilogue, grid 256 x 512thr, lb(512,2)).

#define M_TOK 16384
#define N_PROT 512
#define K_DIM 768
#define BK 32
#define NCH (K_DIM / BK)     // 24
#define ASTR (K_DIM + 8)     // 776: padded LDS row stride in bf16 units

typedef __attribute__((ext_vector_type(4))) float f32x4;
typedef __attribute__((ext_vector_type(8))) short bf16x8;

__device__ inline unsigned short f2bf(float f) {
    // round-to-nearest-even on the bit pattern (finite inputs)
    unsigned int u = __float_as_uint(f);
    u += 0x7fffu + ((u >> 16) & 1u);
    return (unsigned short)(u >> 16);
}

// One wave per prototype row: bf16 convert (fragment-major store) + ||p||^2
// + fp32 passthrough copy.
__global__ __launch_bounds__(256) void prep_b(
    const float* __restrict__ p,
    unsigned short* __restrict__ b_bf, float* __restrict__ p_sq,
    float* __restrict__ proto_out)
{
    const int row  = blockIdx.x * 4 + (threadIdx.x >> 6);
    const int lane = threadIdx.x & 63;

    const int g    = row >> 4;          // proto group 0..31
    const int l16p = row & 15;          // row within group

    const float4* src4 = (const float4*)(p + (size_t)row * K_DIM);
    float4* pout4 = (float4*)(proto_out + (size_t)row * K_DIM);

    float ssum = 0.0f;
#pragma unroll
    for (int j = 0; j < 3; ++j) {        // 192 float4 per row / 64 lanes
        const int idx = lane + j * 64;   // float4 index 0..191
        float4 v = src4[idx];
        ssum += v.x * v.x + v.y * v.y + v.z * v.z + v.w * v.w;
        ushort4 b;
        b.x = f2bf(v.x); b.y = f2bf(v.y); b.z = f2bf(v.z); b.w = f2bf(v.w);
        // fragment-major: element k -> block (g*24 + k>>5), slot
        // ((k>>3)&3)*16 + l16p (lane id), sub-offset k&7.
        const int k0   = idx * 4;               // first element of this ushort4
        const int kk   = k0 >> 5;               // k-step 0..23
        const int quad = (k0 >> 3) & 3;         // k-slice 0..3
        const int j0   = k0 & 7;                // 0 or 4
        const int dst  = (g * 24 + kk) * 512 + quad * 128 + l16p * 8 + j0;
        *(ushort4*)&b_bf[dst] = b;
        pout4[idx] = v;
    }
#pragma unroll
    for (int off = 32; off > 0; off >>= 1) ssum += __shfl_down(ssum, off);
    if (lane == 0) p_sq[row] = ssum;
}

__global__ __launch_bounds__(512, 2) void dist_main(
    const float* __restrict__ X,             // [M,K] fp32 tokens
    const unsigned short* __restrict__ Bb,   // fragment-major bf16 protos (ws)
    const float* __restrict__ p_sq,          // [N] fp32
    float* __restrict__ out)                 // [M,N] fp32 distances
{
    __shared__ unsigned short lds_a[64 * ASTR];   // ~97 KB, full-K A stripe
    __shared__ float lds_xsq[64];

    const int tid  = threadIdx.x;
    const int wave = tid >> 6;           // 0..7
    const int lane = tid & 63;
    const int bm   = blockIdx.x << 6;    // 64-row A stripe
    const int wn   = wave << 6;          // this wave's 64-col slice of N
    const int quad = lane >> 4;          // 0..3
    const int l16  = lane & 15;

    // ---- one-time A staging: fp32 -> (x_sq, bf16 LDS) ----
    const int ar = tid >> 3;             // 0..63 row
    const int ac = tid & 7;              // float4 col base
    const float* aptr = X + (size_t)(bm + ar) * K_DIM;
    float asq = 0.0f;
#pragma unroll
    for (int j = 0; j < 24; ++j) {
        const int c4 = ac + 8 * j;       // float4 index 0..191
        float4 v = *(const float4*)(aptr + (size_t)c4 * 4);
        asq += v.x * v.x + v.y * v.y + v.z * v.z + v.w * v.w;
        ushort4 u;
        u.x = f2bf(v.x); u.y = f2bf(v.y); u.z = f2bf(v.z); u.w = f2bf(v.w);
        *(ushort4*)&lds_a[ar * ASTR + c4 * 4] = u;
    }
#pragma unroll
    for (int off = 1; off < 8; off <<= 1) asq += __shfl_xor(asq, off);
    if (ac == 0) lds_xsq[ar] = asq;

    __syncthreads();   // the ONLY barrier

    // ---- barrier-free K-loop ----
    const f32x4 zero = {0.0f, 0.0f, 0.0f, 0.0f};
    f32x4 acc[4][4];
#pragma unroll
    for (int mt = 0; mt < 4; ++mt)
#pragma unroll
        for (int nt = 0; nt < 4; ++nt) acc[mt][nt] = zero;

    // fragment-major B: block (g*24 + kk) of 1KB; lane's 16B at lane*16.
    // wave's proto groups: g = wave*4 + nt.
    const unsigned short* bp = Bb + (size_t)lane * 8;
    const int gbase = (wave << 2) * 24;          // (wave*4)*24

    bf16x8 bcur[4], bnxt[4];
#pragma unroll
    for (int nt = 0; nt < 4; ++nt)
        bcur[nt] = *(const bf16x8*)(bp + (size_t)(gbase + nt * 24) * 512);

    for (int kc = 0; kc < NCH; ++kc) {
        const int k0 = kc * BK;
        if (kc + 1 < NCH) {
#pragma unroll
            for (int nt = 0; nt < 4; ++nt)
                bnxt[nt] = *(const bf16x8*)(bp
                    + (size_t)(gbase + nt * 24 + kc + 1) * 512);
        }

        bf16x8 af[4];
#pragma unroll
        for (int mt = 0; mt < 4; ++mt)
            af[mt] = *(const bf16x8*)&lds_a[(mt * 16 + l16) * ASTR + k0 + quad * 8];

#pragma unroll
        for (int mt = 0; mt < 4; ++mt)
#pragma unroll
            for (int nt = 0; nt < 4; ++nt)
                acc[mt][nt] = __builtin_amdgcn_mfma_f32_16x16x32_bf16(
                    af[mt], bcur[nt], acc[mt][nt], 0, 0, 0);

#pragma unroll
        for (int nt = 0; nt < 4; ++nt) bcur[nt] = bnxt[nt];
    }

    // ---- epilogue: C/D layout col = lane&15, row = quad*4 + i ----
    float ps[4];
#pragma unroll
    for (int nt = 0; nt < 4; ++nt) ps[nt] = p_sq[wn + nt * 16 + l16];

#pragma unroll
    for (int mt = 0; mt < 4; ++mt) {
#pragma unroll
        for (int i = 0; i < 4; ++i) {
            const int lr = mt * 16 + quad * 4 + i;   // local row 0..63
            const float xs = lds_xsq[lr];
            float* orow = out + (size_t)(bm + lr) * N_PROT + wn + l16;
#pragma unroll
            for (int nt = 0; nt < 4; ++nt)
                orow[nt * 16] = xs + ps[nt] - 2.0f * acc[mt][nt][i];
        }
    }
}

extern "C" void kernel_launch(void* const* d_in, const int* in_sizes, int n_in,
                              void* d_out, int out_size, void* d_ws, size_t ws_size,
                              hipStream_t stream) {
    const float* inputs = (const float*)d_in[0];   // [32,512,768] fp32
    const float* protos = (const float*)d_in[1];   // [512,768]    fp32
    float* out = (float*)d_out;
    float* proto_out = out + (size_t)M_TOK * N_PROT;   // second tuple element

    // ws layout: b_bf 512*768*2 = 786,432 B (fragment-major) ; p_sq 2,048 B
    char* ws = (char*)d_ws;
    unsigned short* b_bf = (unsigned short*)ws;
    float* p_sq = (float*)(ws + 786432);

    prep_b<<<128, 256, 0, stream>>>(protos, b_bf, p_sq, proto_out);
    dist_main<<<M_TOK / 64, 512, 0, stream>>>(inputs, b_bf, p_sq, out);
}